// Round 11
// baseline (7843.917 us; speedup 1.0000x reference)
//
#include <hip/hip_runtime.h>

constexpr int TIN = 50;
constexpr int BLK = 256;
constexpr float NEG_LOG2E = -1.44269504088896341f;

typedef float floatx4 __attribute__((ext_vector_type(4)));

// ws float layout (16B-aligned). ORIGINAL row-major layouts, only scaled:
// col k: s(k) = (k in [20,30), i.e. g-gate) ? 1 : -log2(e)  -> sigmoid = rcp(1+exp2(z'))
//   0    R1s[10][40]
//   400  W1s[40]
//   440  b1s[40]
//   480  W2s[10][40]
//   880  b2s[40]
//   920  R2s[10][40]
//   1320 Wds[12]  (Wd, zero-padded)
constexpr int WS_FLOATS = 1332;

__global__ void prep_weights(const float* __restrict__ W1, const float* __restrict__ R1,
                             const float* __restrict__ b1, const float* __restrict__ W2,
                             const float* __restrict__ R2, const float* __restrict__ b2,
                             const float* __restrict__ Wd, float* __restrict__ ws)
{
    const int tid = threadIdx.x;
    for (int i = tid; i < 400; i += BLK) {
        const int k = i % 40;
        const float s = (k >= 20 && k < 30) ? 1.0f : NEG_LOG2E;
        ws[i]       = R1[i] * s;
        ws[480 + i] = W2[i] * s;
        ws[920 + i] = R2[i] * s;
    }
    for (int k = tid; k < 40; k += BLK) {
        const float s = (k >= 20 && k < 30) ? 1.0f : NEG_LOG2E;
        ws[400 + k] = W1[k] * s;
        ws[440 + k] = b1[k] * s;
        ws[880 + k] = b2[k] * s;
    }
    if (tid < 12) ws[1320 + tid] = (tid < 10) ? Wd[tid] : 0.0f;
}

#define EFMA __builtin_elementwise_fma
#define SB   __builtin_amdgcn_sched_barrier(0);
#define SIGS(x) __builtin_amdgcn_rcpf(1.0f + __builtin_amdgcn_exp2f(x))

#define LD5(d0,d1,d2,d3,d4, P)                                                \
    d0 = (P)[0]; d1 = (P)[1]; d2 = (P)[2]; d3 = (P)[3]; d4 = (P)[4];

#define FMA5(hu, r0,r1,r2,r3,r4)                                              \
    { const float h__ = (hu); const floatx4 hv__ = {h__,h__,h__,h__};         \
      t0 = EFMA(hv__, r0, t0); t1 = EFMA(hv__, r1, t1);                       \
      t2 = EFMA(hv__, r2, t2); t3 = EFMA(hv__, r3, t3);                       \
      t4 = EFMA(hv__, r4, t4); }

// LSTM1 chunk over one gate-pair (qb=0: i,f | qb=5: g,o), 1-unit prefetch
#define CHUNK1(qb)                                                            \
    { const floatx4* Rq_ = (const floatx4*)wsl + (qb);                        \
      const floatx4* Wq_ = (const floatx4*)(wsl + 400) + (qb);                \
      const floatx4* Bq_ = (const floatx4*)(wsl + 440) + (qb);                \
      floatx4 wv0,wv1,wv2,wv3,wv4, ra0,ra1,ra2,ra3,ra4, rb0,rb1,rb2,rb3,rb4;  \
      LD5(t0,t1,t2,t3,t4, Bq_) LD5(wv0,wv1,wv2,wv3,wv4, Wq_) SB               \
      LD5(ra0,ra1,ra2,ra3,ra4, Rq_) SB                                        \
      t0 = EFMA(xs_, wv0, t0); t1 = EFMA(xs_, wv1, t1);                       \
      t2 = EFMA(xs_, wv2, t2); t3 = EFMA(xs_, wv3, t3);                       \
      t4 = EFMA(xs_, wv4, t4); SB                                             \
      LD5(rb0,rb1,rb2,rb3,rb4, Rq_+10) SB FMA5(h0, ra0,ra1,ra2,ra3,ra4) SB    \
      LD5(ra0,ra1,ra2,ra3,ra4, Rq_+20) SB FMA5(h1, rb0,rb1,rb2,rb3,rb4) SB    \
      LD5(rb0,rb1,rb2,rb3,rb4, Rq_+30) SB FMA5(h2, ra0,ra1,ra2,ra3,ra4) SB    \
      LD5(ra0,ra1,ra2,ra3,ra4, Rq_+40) SB FMA5(h3, rb0,rb1,rb2,rb3,rb4) SB    \
      LD5(rb0,rb1,rb2,rb3,rb4, Rq_+50) SB FMA5(h4, ra0,ra1,ra2,ra3,ra4) SB    \
      LD5(ra0,ra1,ra2,ra3,ra4, Rq_+60) SB FMA5(h5, rb0,rb1,rb2,rb3,rb4) SB    \
      LD5(rb0,rb1,rb2,rb3,rb4, Rq_+70) SB FMA5(h6, ra0,ra1,ra2,ra3,ra4) SB    \
      LD5(ra0,ra1,ra2,ra3,ra4, Rq_+80) SB FMA5(h7, rb0,rb1,rb2,rb3,rb4) SB    \
      LD5(rb0,rb1,rb2,rb3,rb4, Rq_+90) SB FMA5(h8, ra0,ra1,ra2,ra3,ra4) SB    \
      FMA5(h9, rb0,rb1,rb2,rb3,rb4) SB }

// non-prefetched 10-unit dot (epilogue only, ~8% of work)
#define DOT10(QP, H0,H1,H2,H3,H4,H5,H6,H7,H8,H9)                              \
    { floatx4 ra0,ra1,ra2,ra3,ra4;                                            \
      LD5(ra0,ra1,ra2,ra3,ra4,(QP)+ 0) SB FMA5(H0, ra0,ra1,ra2,ra3,ra4) SB    \
      LD5(ra0,ra1,ra2,ra3,ra4,(QP)+10) SB FMA5(H1, ra0,ra1,ra2,ra3,ra4) SB    \
      LD5(ra0,ra1,ra2,ra3,ra4,(QP)+20) SB FMA5(H2, ra0,ra1,ra2,ra3,ra4) SB    \
      LD5(ra0,ra1,ra2,ra3,ra4,(QP)+30) SB FMA5(H3, ra0,ra1,ra2,ra3,ra4) SB    \
      LD5(ra0,ra1,ra2,ra3,ra4,(QP)+40) SB FMA5(H4, ra0,ra1,ra2,ra3,ra4) SB    \
      LD5(ra0,ra1,ra2,ra3,ra4,(QP)+50) SB FMA5(H5, ra0,ra1,ra2,ra3,ra4) SB    \
      LD5(ra0,ra1,ra2,ra3,ra4,(QP)+60) SB FMA5(H6, ra0,ra1,ra2,ra3,ra4) SB    \
      LD5(ra0,ra1,ra2,ra3,ra4,(QP)+70) SB FMA5(H7, ra0,ra1,ra2,ra3,ra4) SB    \
      LD5(ra0,ra1,ra2,ra3,ra4,(QP)+80) SB FMA5(H8, ra0,ra1,ra2,ra3,ra4) SB    \
      LD5(ra0,ra1,ra2,ra3,ra4,(QP)+90) SB FMA5(H9, ra0,ra1,ra2,ra3,ra4) SB }

// element k (0..19) of the t0..t4 quad group / of an explicit quad group
#define EL(k)  ((k)<4?t0[(k)]:(k)<8?t1[(k)-4]:(k)<12?t2[(k)-8]:(k)<16?t3[(k)-12]:t4[(k)-16])
#define ELX(a0,a1,a2,a3,a4,k) \
    ((k)<4?(a0)[(k)]:(k)<8?(a1)[(k)-4]:(k)<12?(a2)[(k)-8]:(k)<16?(a3)[(k)-12]:(a4)[(k)-16])

// chunk B (g,o) activations: pg = relu(g), po = sig(o)
#define ACTB(j) pg##j = fmaxf(EL(j), 0.0f); po##j = SIGS(EL(10+(j)));
// LSTM1 chunk A (i,f) activations + state update
#define ACTA(j) c##j = fmaf(SIGS(EL(10+(j))), c##j, SIGS(EL(j)) * pg##j);     \
                h##j = po##j * fmaxf(c##j, 0.0f);
// LSTM2 version (state ca/ha)
#define ACT2A(j) ca##j = fmaf(SIGS(EL(10+(j))), ca##j, SIGS(EL(j)) * pg##j);  \
                 ha##j = po##j * fmaxf(ca##j, 0.0f);

#define STEP1(xval)                                                           \
    { int aoff_ = 0; asm volatile("" : "+v"(aoff_));                          \
      const float* wsl = smem + aoff_;                                        \
      const float x_ = (xval); const floatx4 xs_ = {x_,x_,x_,x_};             \
      floatx4 t0,t1,t2,t3,t4;                                                 \
      float pg0,pg1,pg2,pg3,pg4,pg5,pg6,pg7,pg8,pg9;                          \
      float po0,po1,po2,po3,po4,po5,po6,po7,po8,po9;                          \
      CHUNK1(5)                                                               \
      ACTB(0) ACTB(1) ACTB(2) ACTB(3) ACTB(4)                                 \
      ACTB(5) ACTB(6) ACTB(7) ACTB(8) ACTB(9) SB                              \
      CHUNK1(0)                                                               \
      ACTA(0) ACTA(1) ACTA(2) ACTA(3) ACTA(4)                                 \
      ACTA(5) ACTA(6) ACTA(7) ACTA(8) ACTA(9) SB }

#define STEP2                                                                 \
    { const float hb0=ha0,hb1=ha1,hb2=ha2,hb3=ha3,hb4=ha4;                    \
      const float hb5=ha5,hb6=ha6,hb7=ha7,hb8=ha8,hb9=ha9;                    \
      floatx4 t0,t1,t2,t3,t4;                                                 \
      float pg0,pg1,pg2,pg3,pg4,pg5,pg6,pg7,pg8,pg9;                          \
      float po0,po1,po2,po3,po4,po5,po6,po7,po8,po9;                          \
      t0=xb0; t1=xb1; t2=xb2; t3=xb3; t4=xb4;                                 \
      DOT10((const floatx4*)(wsl+920)+5, hb0,hb1,hb2,hb3,hb4,hb5,hb6,hb7,hb8,hb9) \
      ACTB(0) ACTB(1) ACTB(2) ACTB(3) ACTB(4)                                 \
      ACTB(5) ACTB(6) ACTB(7) ACTB(8) ACTB(9) SB                              \
      t0=xa0; t1=xa1; t2=xa2; t3=xa3; t4=xa4;                                 \
      DOT10((const floatx4*)(wsl+920)+0, hb0,hb1,hb2,hb3,hb4,hb5,hb6,hb7,hb8,hb9) \
      ACT2A(0) ACT2A(1) ACT2A(2) ACT2A(3) ACT2A(4)                            \
      ACT2A(5) ACT2A(6) ACT2A(7) ACT2A(8) ACT2A(9) SB }

__global__ __launch_bounds__(BLK, 4)
void lstm_ae_kernel(const float* __restrict__ X, const float* __restrict__ ws,
                    const float* __restrict__ bd, float* __restrict__ out, int B)
{
    __shared__ __align__(16) float smem[WS_FLOATS];    // 5.3 KB
    for (int i = threadIdx.x; i < WS_FLOATS; i += BLK) smem[i] = ws[i];
    __syncthreads();

    const int b = blockIdx.x * BLK + threadIdx.x;
    if (b >= B) return;

    // ---------------- LSTM 1: 50 steps ----------------
    float h0=0,h1=0,h2=0,h3=0,h4=0,h5=0,h6=0,h7=0,h8=0,h9=0;
    float c0=0,c1=0,c2=0,c3=0,c4=0,c5=0,c6=0,c7=0,c8=0,c9=0;

    const float2* __restrict__ xp = (const float2*)(X + (size_t)b * TIN);
    float2 xv = xp[0];
    #pragma unroll 1
    for (int p = 0; p < TIN / 2 - 1; ++p) {
        const float2 xn = xp[p + 1];
        STEP1(xv.x)
        STEP1(xv.y)
        xv = xn;
    }
    STEP1(xv.x)
    STEP1(xv.y)

    // ---------------- RepeatVector(3) + LSTM 2 + Dense ----------------
    const float* wsl = smem;
    floatx4 xa0,xa1,xa2,xa3,xa4, xb0,xb1,xb2,xb3,xb4;
    {   floatx4 t0,t1,t2,t3,t4;
        LD5(t0,t1,t2,t3,t4, (const floatx4*)(wsl+880)+5) SB
        DOT10((const floatx4*)(wsl+480)+5, h0,h1,h2,h3,h4,h5,h6,h7,h8,h9)
        xb0=t0; xb1=t1; xb2=t2; xb3=t3; xb4=t4;
        LD5(t0,t1,t2,t3,t4, (const floatx4*)(wsl+880)+0) SB
        DOT10((const floatx4*)(wsl+480)+0, h0,h1,h2,h3,h4,h5,h6,h7,h8,h9)
        xa0=t0; xa1=t1; xa2=t2; xa3=t3; xa4=t4;
    }

    const float wd0=wsl[1320],wd1=wsl[1321],wd2=wsl[1322],wd3=wsl[1323],wd4=wsl[1324];
    const float wd5=wsl[1325],wd6=wsl[1326],wd7=wsl[1327],wd8=wsl[1328],wd9=wsl[1329];
    const float bd0 = bd[0];

    // t2 = 0: h_prev = c_prev = 0 -> c = sig(i)*relu(g); h = sig(o)*relu(c)
    float ha0,ha1,ha2,ha3,ha4,ha5,ha6,ha7,ha8,ha9;
    float ca0,ca1,ca2,ca3,ca4,ca5,ca6,ca7,ca8,ca9;
#define T20(j)                                                                \
    ca##j = SIGS(ELX(xa0,xa1,xa2,xa3,xa4,(j)))                                \
            * fmaxf(ELX(xb0,xb1,xb2,xb3,xb4,(j)), 0.0f);                      \
    ha##j = SIGS(ELX(xb0,xb1,xb2,xb3,xb4,10+(j))) * fmaxf(ca##j, 0.0f);
    T20(0) T20(1) T20(2) T20(3) T20(4) T20(5) T20(6) T20(7) T20(8) T20(9)
#undef T20

#define DSUM(dst)                                                             \
    dst = bd0; dst = fmaf(ha0,wd0,dst); dst = fmaf(ha1,wd1,dst);              \
    dst = fmaf(ha2,wd2,dst); dst = fmaf(ha3,wd3,dst); dst = fmaf(ha4,wd4,dst);\
    dst = fmaf(ha5,wd5,dst); dst = fmaf(ha6,wd6,dst); dst = fmaf(ha7,wd7,dst);\
    dst = fmaf(ha8,wd8,dst); dst = fmaf(ha9,wd9,dst);

    float ov0, ov1, ov2;
    DSUM(ov0)
    STEP2
    DSUM(ov1)
    STEP2
    DSUM(ov2)

    float* __restrict__ o3 = out + (size_t)b * 3;
    o3[0] = ov0;
    o3[1] = ov1;
    o3[2] = ov2;
}

extern "C" void kernel_launch(void* const* d_in, const int* in_sizes, int n_in,
                              void* d_out, int out_size, void* d_ws, size_t ws_size,
                              hipStream_t stream) {
    const float* X  = (const float*)d_in[0];
    const float* W1 = (const float*)d_in[1];
    const float* R1 = (const float*)d_in[2];
    const float* b1 = (const float*)d_in[3];
    const float* W2 = (const float*)d_in[4];
    const float* R2 = (const float*)d_in[5];
    const float* b2 = (const float*)d_in[6];
    const float* Wd = (const float*)d_in[7];
    const float* bd = (const float*)d_in[8];
    float* out = (float*)d_out;
    float* ws  = (float*)d_ws;

    const int B = in_sizes[0] / TIN;   // 524288
    prep_weights<<<1, BLK, 0, stream>>>(W1, R1, b1, W2, R2, b2, Wd, ws);
    const int grid = (B + BLK - 1) / BLK;   // 2048
    lstm_ae_kernel<<<grid, BLK, 0, stream>>>(X, ws, bd, out, B);
}

// Round 12
// 517.793 us; speedup vs baseline: 15.1488x; 15.1488x over previous
//
#include <hip/hip_runtime.h>

constexpr int TIN = 50;
constexpr int BLK = 512;          // round 12: 8 waves/block (was 256) — occupancy-cap probe
constexpr float NEG_LOG2E = -1.44269504088896341f;

typedef float floatx4 __attribute__((ext_vector_type(4)));

// ws float layout (16B-aligned, gate-major, 10->12 pad so quads are single-gate).
// k = gate*12 + j, gate {0:i,1:f,2:g,3:o}; i/f/o cols pre-scaled by -log2(e)
// so sigmoid(z) = rcp(1 + exp2(z')).
//   0    R1p[10][48]
//   480  W1p[48]
//   528  b1p[48]
//   576  W2p[10][48]
//   1056 b2p[48]
//   1104 R2p[10][48]
//   1584 Wdp[12]
constexpr int WS_FLOATS = 1596;

__global__ void prep_weights(const float* __restrict__ W1, const float* __restrict__ R1,
                             const float* __restrict__ b1, const float* __restrict__ W2,
                             const float* __restrict__ R2, const float* __restrict__ b2,
                             const float* __restrict__ Wd, float* __restrict__ ws)
{
    const int tid = threadIdx.x;
    for (int i = tid; i < 480; i += BLK) {
        const int u = i / 48, k = i % 48, gate = k / 12, j = k % 12;
        const float sg = (gate == 2) ? 1.0f : NEG_LOG2E;
        ws[i]        = (j < 10) ? R1[u * 40 + gate * 10 + j] * sg : 0.0f;
        ws[576 + i]  = (j < 10) ? W2[u * 40 + gate * 10 + j] * sg : 0.0f;
        ws[1104 + i] = (j < 10) ? R2[u * 40 + gate * 10 + j] * sg : 0.0f;
    }
    for (int k = tid; k < 48; k += BLK) {
        const int gate = k / 12, j = k % 12;
        const float sg = (gate == 2) ? 1.0f : NEG_LOG2E;
        ws[480 + k]  = (j < 10) ? W1[gate * 10 + j] * sg : 0.0f;
        ws[528 + k]  = (j < 10) ? b1[gate * 10 + j] * sg : 0.0f;
        ws[1056 + k] = (j < 10) ? b2[gate * 10 + j] * sg : 0.0f;
    }
    if (tid < 12) ws[1584 + tid] = (tid < 10) ? Wd[tid] : 0.0f;
}

#define EFMA __builtin_elementwise_fma
#define EMAX __builtin_elementwise_max
#define SB   __builtin_amdgcn_sched_barrier(0);

#define SIGQ(dst, src)                                                        \
    dst[0] = __builtin_amdgcn_rcpf(1.0f + __builtin_amdgcn_exp2f((src)[0]));  \
    dst[1] = __builtin_amdgcn_rcpf(1.0f + __builtin_amdgcn_exp2f((src)[1]));  \
    dst[2] = __builtin_amdgcn_rcpf(1.0f + __builtin_amdgcn_exp2f((src)[2]));  \
    dst[3] = __builtin_amdgcn_rcpf(1.0f + __builtin_amdgcn_exp2f((src)[3]));

#define SIG3(d0, d1, d2, s0, s1, s2) SIGQ(d0, s0) SIGQ(d1, s1) SIGQ(d2, s2)

// t{0,1,2} += HV * RB[u*12 + g*3 + {0,1,2}]   (one source unit, one gate)
#define RECQ(RB, g, u, HV, t0, t1, t2)                                        \
    {   const float h_ = (HV);                                                \
        const floatx4 hs_ = {h_, h_, h_, h_};                                 \
        t0 = EFMA(hs_, RB[(u) * 12 + (g) * 3 + 0], t0);                       \
        t1 = EFMA(hs_, RB[(u) * 12 + (g) * 3 + 1], t1);                       \
        t2 = EFMA(hs_, RB[(u) * 12 + (g) * 3 + 2], t2); }

// full 10-unit recurrence for one gate; sched_barrier every 2 units bounds
// the number of in-flight ds_read_b128 results (<=6 quads transient) and sits
// at a CONSUMPTION boundary (nothing loaded-but-unused crosses the SB)
#define REC10(RB, g, H0, H1, H2, t0, t1, t2)                                  \
    RECQ(RB, g, 0, (H0)[0], t0, t1, t2) RECQ(RB, g, 1, (H0)[1], t0, t1, t2) SB\
    RECQ(RB, g, 2, (H0)[2], t0, t1, t2) RECQ(RB, g, 3, (H0)[3], t0, t1, t2) SB\
    RECQ(RB, g, 4, (H1)[0], t0, t1, t2) RECQ(RB, g, 5, (H1)[1], t0, t1, t2) SB\
    RECQ(RB, g, 6, (H1)[2], t0, t1, t2) RECQ(RB, g, 7, (H1)[3], t0, t1, t2) SB\
    RECQ(RB, g, 8, (H2)[0], t0, t1, t2) RECQ(RB, g, 9, (H2)[1], t0, t1, t2) SB

// LSTM1 gate pre-activation: t = x*W1p[g] + b1p[g] + h @ R1p[:,g]
#define GATE1(g, t0, t1, t2)                                                  \
    t0 = EFMA(xs_, Wq_[(g) * 3 + 0], Bq_[(g) * 3 + 0]);                       \
    t1 = EFMA(xs_, Wq_[(g) * 3 + 1], Bq_[(g) * 3 + 1]);                       \
    t2 = EFMA(xs_, Wq_[(g) * 3 + 2], Bq_[(g) * 3 + 2]);                       \
    REC10(Rq_, g, hq0, hq1, hq2, t0, t1, t2)

// One LSTM1 step, gate-chunked g -> i -> f -> o. All state in named quads.
#define STEP(xval)                                                            \
    {   int lof_ = 0;                                                         \
        asm volatile("" : "+v"(lof_));    /* block LICM of invariant loads */ \
        const floatx4* Rq_ = (const floatx4*)(smem + lof_);                   \
        const floatx4* Wq_ = (const floatx4*)(smem + 480 + lof_);             \
        const floatx4* Bq_ = (const floatx4*)(smem + 528 + lof_);             \
        const float x_ = (xval);                                              \
        const floatx4 xs_ = {x_, x_, x_, x_};                                 \
        floatx4 t0, t1, t2, p0, p1, p2, q0, q1, q2;                           \
        GATE1(2, t0, t1, t2)   /* g: relu */                                  \
        p0 = EMAX(t0, zero4); p1 = EMAX(t1, zero4); p2 = EMAX(t2, zero4); SB  \
        GATE1(0, t0, t1, t2)   /* i */                                        \
        SIG3(q0, q1, q2, t0, t1, t2)                                          \
        p0 *= q0; p1 *= q1; p2 *= q2; SB                                      \
        GATE1(1, t0, t1, t2)   /* f */                                        \
        SIG3(q0, q1, q2, t0, t1, t2)                                          \
        cq0 = EFMA(q0, cq0, p0); cq1 = EFMA(q1, cq1, p1);                     \
        cq2 = EFMA(q2, cq2, p2); SB                                           \
        GATE1(3, t0, t1, t2)   /* o (dot uses old h; h written after) */      \
        SIG3(q0, q1, q2, t0, t1, t2)                                          \
        hq0 = q0 * EMAX(cq0, zero4); hq1 = q1 * EMAX(cq1, zero4);             \
        hq2 = q2 * EMAX(cq2, zero4); SB                                       \
    }

// xz gate construction: xq = b2p[g] + h1 @ W2p[:,g]
#define XZG(g, x0, x1, x2)                                                    \
    x0 = B2q_[(g) * 3 + 0]; x1 = B2q_[(g) * 3 + 1]; x2 = B2q_[(g) * 3 + 2];   \
    REC10(W2q_, g, hq0, hq1, hq2, x0, x1, x2)

// LSTM2 gate pre-activation for t2>=1: t = xz[g] + h2_old @ R2p[:,g]
#define GATE2(g, i0, i1, i2, t0, t1, t2)                                      \
    t0 = i0; t1 = i1; t2 = i2;                                                \
    REC10(R2q_, g, ho0, ho1, ho2, t0, t1, t2)

#define STEP2                                                                 \
    {   const floatx4 ho0 = h2q0, ho1 = h2q1, ho2 = h2q2;                     \
        floatx4 tt0, tt1, tt2, pp0, pp1, pp2, qq0, qq1, qq2;                  \
        GATE2(2, xqg0, xqg1, xqg2, tt0, tt1, tt2)                             \
        pp0 = EMAX(tt0, zero4); pp1 = EMAX(tt1, zero4);                       \
        pp2 = EMAX(tt2, zero4); SB                                            \
        GATE2(0, xqi0, xqi1, xqi2, tt0, tt1, tt2)                             \
        SIG3(qq0, qq1, qq2, tt0, tt1, tt2)                                    \
        pp0 *= qq0; pp1 *= qq1; pp2 *= qq2; SB                                \
        GATE2(1, xqf0, xqf1, xqf2, tt0, tt1, tt2)                             \
        SIG3(qq0, qq1, qq2, tt0, tt1, tt2)                                    \
        c2q0 = EFMA(qq0, c2q0, pp0); c2q1 = EFMA(qq1, c2q1, pp1);             \
        c2q2 = EFMA(qq2, c2q2, pp2); SB                                       \
        GATE2(3, xqo0, xqo1, xqo2, tt0, tt1, tt2)                             \
        SIG3(qq0, qq1, qq2, tt0, tt1, tt2)                                    \
        h2q0 = qq0 * EMAX(c2q0, zero4); h2q1 = qq1 * EMAX(c2q1, zero4);       \
        h2q2 = qq2 * EMAX(c2q2, zero4); SB                                    \
    }

#define DOUT(dst)                                                             \
    {   floatx4 dv_ = h2q0 * Wdq_[0];                                         \
        dv_ = EFMA(h2q1, Wdq_[1], dv_);                                       \
        dv_ = EFMA(h2q2, Wdq_[2], dv_);                                       \
        dst = dv_[0] + dv_[1] + dv_[2] + dv_[3] + bd0; }

__global__ __launch_bounds__(BLK, 4)
void lstm_ae_kernel(const float* __restrict__ X, const float* __restrict__ ws,
                    const float* __restrict__ bd, float* __restrict__ out, int B)
{
    __shared__ __align__(16) float smem[WS_FLOATS];    // 6.4 KB
    for (int i = threadIdx.x; i < WS_FLOATS; i += BLK) smem[i] = ws[i];
    __syncthreads();

    const int b = blockIdx.x * BLK + threadIdx.x;
    if (b >= B) return;

    const floatx4 zero4 = {0.0f, 0.0f, 0.0f, 0.0f};

    // ---------------- LSTM 1: 50 steps ----------------
    floatx4 hq0 = zero4, hq1 = zero4, hq2 = zero4;
    floatx4 cq0 = zero4, cq1 = zero4, cq2 = zero4;

    const float2* __restrict__ xp = (const float2*)(X + (size_t)b * TIN);
    float2 xv = xp[0];
    #pragma unroll 1
    for (int p = 0; p < TIN / 2 - 1; ++p) {
        const float2 xn = xp[p + 1];
        STEP(xv.x)
        STEP(xv.y)
        xv = xn;
    }
    STEP(xv.x)
    STEP(xv.y)

    // ---------------- RepeatVector(3) + LSTM 2 + Dense ----------------
    const floatx4* W2q_ = (const floatx4*)(smem + 576);
    const floatx4* B2q_ = (const floatx4*)(smem + 1056);
    const floatx4* R2q_ = (const floatx4*)(smem + 1104);
    const floatx4* Wdq_ = (const floatx4*)(smem + 1584);
    const float bd0 = bd[0];

    floatx4 xqi0, xqi1, xqi2, xqf0, xqf1, xqf2;
    floatx4 xqg0, xqg1, xqg2, xqo0, xqo1, xqo2;
    XZG(0, xqi0, xqi1, xqi2) SB
    XZG(1, xqf0, xqf1, xqf2) SB
    XZG(2, xqg0, xqg1, xqg2) SB
    XZG(3, xqo0, xqo1, xqo2) SB

    floatx4 c2q0, c2q1, c2q2, h2q0, h2q1, h2q2, q0, q1, q2, s0, s1, s2;
    // t2 = 0: h_prev = c_prev = 0 -> c = sig(i)*relu(g)
    SIG3(q0, q1, q2, xqi0, xqi1, xqi2)
    c2q0 = q0 * EMAX(xqg0, zero4);
    c2q1 = q1 * EMAX(xqg1, zero4);
    c2q2 = q2 * EMAX(xqg2, zero4);
    SIG3(s0, s1, s2, xqo0, xqo1, xqo2)
    h2q0 = s0 * EMAX(c2q0, zero4);
    h2q1 = s1 * EMAX(c2q1, zero4);
    h2q2 = s2 * EMAX(c2q2, zero4);
    float o0; DOUT(o0)
    float o1; STEP2 DOUT(o1)
    float o2; STEP2 DOUT(o2)

    float* __restrict__ o3 = out + (size_t)b * 3;
    o3[0] = o0;
    o3[1] = o1;
    o3[2] = o2;
}

extern "C" void kernel_launch(void* const* d_in, const int* in_sizes, int n_in,
                              void* d_out, int out_size, void* d_ws, size_t ws_size,
                              hipStream_t stream) {
    const float* X  = (const float*)d_in[0];
    const float* W1 = (const float*)d_in[1];
    const float* R1 = (const float*)d_in[2];
    const float* b1 = (const float*)d_in[3];
    const float* W2 = (const float*)d_in[4];
    const float* R2 = (const float*)d_in[5];
    const float* b2 = (const float*)d_in[6];
    const float* Wd = (const float*)d_in[7];
    const float* bd = (const float*)d_in[8];
    float* out = (float*)d_out;
    float* ws  = (float*)d_ws;

    const int B = in_sizes[0] / TIN;   // 524288
    prep_weights<<<1, BLK, 0, stream>>>(W1, R1, b1, W2, R2, b2, Wd, ws);
    const int grid = (B + BLK - 1) / BLK;   // 1024
    lstm_ae_kernel<<<grid, BLK, 0, stream>>>(X, ws, bd, out, B);
}

// Round 13
// 473.437 us; speedup vs baseline: 16.5680x; 1.0937x over previous
//
#include <hip/hip_runtime.h>

constexpr int TIN = 50;
constexpr int BLK = 256;
constexpr float NEG_LOG2E = -1.44269504088896341f;

typedef float floatx4 __attribute__((ext_vector_type(4)));

// ws float layout (16B-aligned, gate-major, 10->12 pad so quads are single-gate).
// k = gate*12 + j, gate {0:i,1:f,2:g,3:o}; i/f/o cols pre-scaled by -log2(e)
// so sigmoid(z) = rcp(1 + exp2(z')).
//   0    R1p[10][48]
//   480  W1p[48]
//   528  b1p[48]
//   576  W2p[10][48]
//   1056 b2p[48]
//   1104 R2p[10][48]
//   1584 Wdp[12]
constexpr int WS_FLOATS = 1596;

__global__ void prep_weights(const float* __restrict__ W1, const float* __restrict__ R1,
                             const float* __restrict__ b1, const float* __restrict__ W2,
                             const float* __restrict__ R2, const float* __restrict__ b2,
                             const float* __restrict__ Wd, float* __restrict__ ws)
{
    const int tid = threadIdx.x;
    for (int i = tid; i < 480; i += BLK) {
        const int u = i / 48, k = i % 48, gate = k / 12, j = k % 12;
        const float sg = (gate == 2) ? 1.0f : NEG_LOG2E;
        ws[i]        = (j < 10) ? R1[u * 40 + gate * 10 + j] * sg : 0.0f;
        ws[576 + i]  = (j < 10) ? W2[u * 40 + gate * 10 + j] * sg : 0.0f;
        ws[1104 + i] = (j < 10) ? R2[u * 40 + gate * 10 + j] * sg : 0.0f;
    }
    for (int k = tid; k < 48; k += BLK) {
        const int gate = k / 12, j = k % 12;
        const float sg = (gate == 2) ? 1.0f : NEG_LOG2E;
        ws[480 + k]  = (j < 10) ? W1[gate * 10 + j] * sg : 0.0f;
        ws[528 + k]  = (j < 10) ? b1[gate * 10 + j] * sg : 0.0f;
        ws[1056 + k] = (j < 10) ? b2[gate * 10 + j] * sg : 0.0f;
    }
    if (tid < 12) ws[1584 + tid] = (tid < 10) ? Wd[tid] : 0.0f;
}

#define EFMA __builtin_elementwise_fma
#define EMAX __builtin_elementwise_max
#define SB   __builtin_amdgcn_sched_barrier(0);

#define SIGQ(dst, src)                                                        \
    dst[0] = __builtin_amdgcn_rcpf(1.0f + __builtin_amdgcn_exp2f((src)[0]));  \
    dst[1] = __builtin_amdgcn_rcpf(1.0f + __builtin_amdgcn_exp2f((src)[1]));  \
    dst[2] = __builtin_amdgcn_rcpf(1.0f + __builtin_amdgcn_exp2f((src)[2]));  \
    dst[3] = __builtin_amdgcn_rcpf(1.0f + __builtin_amdgcn_exp2f((src)[3]));

#define SIG3(d0, d1, d2, s0, s1, s2) SIGQ(d0, s0) SIGQ(d1, s1) SIGQ(d2, s2)

// ---------------- single-element building blocks (epilogue; = round 10) -----
#define RECQ(RB, g, u, HV, t0, t1, t2)                                        \
    {   const float h_ = (HV);                                                \
        const floatx4 hs_ = {h_, h_, h_, h_};                                 \
        t0 = EFMA(hs_, RB[(u) * 12 + (g) * 3 + 0], t0);                       \
        t1 = EFMA(hs_, RB[(u) * 12 + (g) * 3 + 1], t1);                       \
        t2 = EFMA(hs_, RB[(u) * 12 + (g) * 3 + 2], t2); }

#define REC10(RB, g, H0, H1, H2, t0, t1, t2)                                  \
    RECQ(RB, g, 0, (H0)[0], t0, t1, t2) RECQ(RB, g, 1, (H0)[1], t0, t1, t2) SB\
    RECQ(RB, g, 2, (H0)[2], t0, t1, t2) RECQ(RB, g, 3, (H0)[3], t0, t1, t2) SB\
    RECQ(RB, g, 4, (H1)[0], t0, t1, t2) RECQ(RB, g, 5, (H1)[1], t0, t1, t2) SB\
    RECQ(RB, g, 6, (H1)[2], t0, t1, t2) RECQ(RB, g, 7, (H1)[3], t0, t1, t2) SB\
    RECQ(RB, g, 8, (H2)[0], t0, t1, t2) RECQ(RB, g, 9, (H2)[1], t0, t1, t2) SB

#define XZG(g, x0, x1, x2)                                                    \
    x0 = B2q_[(g) * 3 + 0]; x1 = B2q_[(g) * 3 + 1]; x2 = B2q_[(g) * 3 + 2];   \
    REC10(W2q_, g, hq0, hq1, hq2, x0, x1, x2)

#define GATE2(g, i0, i1, i2, t0, t1, t2)                                      \
    t0 = i0; t1 = i1; t2 = i2;                                                \
    REC10(R2q_, g, ho0, ho1, ho2, t0, t1, t2)

#define STEP2T                                                                \
    {   const floatx4 ho0 = h2q0, ho1 = h2q1, ho2 = h2q2;                     \
        floatx4 tt0, tt1, tt2, pp0, pp1, pp2, qq0, qq1, qq2;                  \
        GATE2(2, xqg0, xqg1, xqg2, tt0, tt1, tt2)                             \
        pp0 = EMAX(tt0, zero4); pp1 = EMAX(tt1, zero4);                       \
        pp2 = EMAX(tt2, zero4); SB                                            \
        GATE2(0, xqi0, xqi1, xqi2, tt0, tt1, tt2)                             \
        SIG3(qq0, qq1, qq2, tt0, tt1, tt2)                                    \
        pp0 *= qq0; pp1 *= qq1; pp2 *= qq2; SB                                \
        GATE2(1, xqf0, xqf1, xqf2, tt0, tt1, tt2)                             \
        SIG3(qq0, qq1, qq2, tt0, tt1, tt2)                                    \
        c2q0 = EFMA(qq0, c2q0, pp0); c2q1 = EFMA(qq1, c2q1, pp1);             \
        c2q2 = EFMA(qq2, c2q2, pp2); SB                                       \
        GATE2(3, xqo0, xqo1, xqo2, tt0, tt1, tt2)                             \
        SIG3(qq0, qq1, qq2, tt0, tt1, tt2)                                    \
        h2q0 = qq0 * EMAX(c2q0, zero4); h2q1 = qq1 * EMAX(c2q1, zero4);       \
        h2q2 = qq2 * EMAX(c2q2, zero4); SB                                    \
    }

#define DOUT(dst)                                                             \
    {   floatx4 dv_ = h2q0 * Wdq_[0];                                         \
        dv_ = EFMA(h2q1, Wdq_[1], dv_);                                       \
        dv_ = EFMA(h2q2, Wdq_[2], dv_);                                       \
        dst = dv_[0] + dv_[1] + dv_[2] + dv_[3] + bd0; }

// RepeatVector(3) + LSTM2 + Dense for ONE element (all names compile-time)
__device__ __forceinline__ void tail_one(const float* __restrict__ smem,
                                         floatx4 hq0, floatx4 hq1, floatx4 hq2,
                                         float bd0, float* __restrict__ o3)
{
    const floatx4 zero4 = {0.0f, 0.0f, 0.0f, 0.0f};
    const floatx4* W2q_ = (const floatx4*)(smem + 576);
    const floatx4* B2q_ = (const floatx4*)(smem + 1056);
    const floatx4* R2q_ = (const floatx4*)(smem + 1104);
    const floatx4* Wdq_ = (const floatx4*)(smem + 1584);

    floatx4 xqi0, xqi1, xqi2, xqf0, xqf1, xqf2;
    floatx4 xqg0, xqg1, xqg2, xqo0, xqo1, xqo2;
    XZG(0, xqi0, xqi1, xqi2) SB
    XZG(1, xqf0, xqf1, xqf2) SB
    XZG(2, xqg0, xqg1, xqg2) SB
    XZG(3, xqo0, xqo1, xqo2) SB

    floatx4 c2q0, c2q1, c2q2, h2q0, h2q1, h2q2, q0, q1, q2, s0, s1, s2;
    SIG3(q0, q1, q2, xqi0, xqi1, xqi2)
    c2q0 = q0 * EMAX(xqg0, zero4);
    c2q1 = q1 * EMAX(xqg1, zero4);
    c2q2 = q2 * EMAX(xqg2, zero4);
    SIG3(s0, s1, s2, xqo0, xqo1, xqo2)
    h2q0 = s0 * EMAX(c2q0, zero4);
    h2q1 = s1 * EMAX(c2q1, zero4);
    h2q2 = s2 * EMAX(c2q2, zero4);
    float o0; DOUT(o0)
    float o1; STEP2T DOUT(o1)
    float o2; STEP2T DOUT(o2)
    o3[0] = o0; o3[1] = o1; o3[2] = o2;
}

// ---------------- M=2 main-loop building blocks ----------------------------
// One source unit, shared quad loads (CSE -> 3 ds_read_b128), 6 quad-FMAs.
#define RECQ2(RB, g, u, HA, HB)                                               \
    {   const float ha_ = (HA), hb_ = (HB);                                   \
        const floatx4 hav_ = {ha_, ha_, ha_, ha_};                            \
        const floatx4 hbv_ = {hb_, hb_, hb_, hb_};                            \
        const floatx4 r0_ = RB[(u) * 12 + (g) * 3 + 0];                       \
        const floatx4 r1_ = RB[(u) * 12 + (g) * 3 + 1];                       \
        const floatx4 r2_ = RB[(u) * 12 + (g) * 3 + 2];                       \
        tA0 = EFMA(hav_, r0_, tA0); tB0 = EFMA(hbv_, r0_, tB0);               \
        tA1 = EFMA(hav_, r1_, tA1); tB1 = EFMA(hbv_, r1_, tB1);               \
        tA2 = EFMA(hav_, r2_, tA2); tB2 = EFMA(hbv_, r2_, tB2); }

#define REC10_2(RB, g)                                                        \
    RECQ2(RB, g, 0, hA0[0], hB0[0]) RECQ2(RB, g, 1, hA0[1], hB0[1]) SB        \
    RECQ2(RB, g, 2, hA0[2], hB0[2]) RECQ2(RB, g, 3, hA0[3], hB0[3]) SB        \
    RECQ2(RB, g, 4, hA1[0], hB1[0]) RECQ2(RB, g, 5, hA1[1], hB1[1]) SB        \
    RECQ2(RB, g, 6, hA1[2], hB1[2]) RECQ2(RB, g, 7, hA1[3], hB1[3]) SB        \
    RECQ2(RB, g, 8, hA2[0], hB2[0]) RECQ2(RB, g, 9, hA2[1], hB2[1]) SB

#define GATE1_2(g)                                                            \
    tA0 = EFMA(xsA_, Wq_[(g) * 3 + 0], Bq_[(g) * 3 + 0]);                     \
    tB0 = EFMA(xsB_, Wq_[(g) * 3 + 0], Bq_[(g) * 3 + 0]);                     \
    tA1 = EFMA(xsA_, Wq_[(g) * 3 + 1], Bq_[(g) * 3 + 1]);                     \
    tB1 = EFMA(xsB_, Wq_[(g) * 3 + 1], Bq_[(g) * 3 + 1]);                     \
    tA2 = EFMA(xsA_, Wq_[(g) * 3 + 2], Bq_[(g) * 3 + 2]);                     \
    tB2 = EFMA(xsB_, Wq_[(g) * 3 + 2], Bq_[(g) * 3 + 2]);                     \
    REC10_2(Rq_, g)

#define STEP1_2(xa, xb)                                                       \
    {   int lof_ = 0;                                                         \
        asm volatile("" : "+v"(lof_));    /* block LICM of invariant loads */ \
        const floatx4* Rq_ = (const floatx4*)(smem + lof_);                   \
        const floatx4* Wq_ = (const floatx4*)(smem + 480 + lof_);             \
        const floatx4* Bq_ = (const floatx4*)(smem + 528 + lof_);             \
        const float xa_ = (xa), xb_ = (xb);                                   \
        const floatx4 xsA_ = {xa_, xa_, xa_, xa_};                            \
        const floatx4 xsB_ = {xb_, xb_, xb_, xb_};                            \
        floatx4 tA0, tA1, tA2, tB0, tB1, tB2;                                 \
        floatx4 pA0, pA1, pA2, pB0, pB1, pB2;                                 \
        floatx4 qA0, qA1, qA2, qB0, qB1, qB2;                                 \
        GATE1_2(2)   /* g: relu */                                            \
        pA0 = EMAX(tA0, zero4); pA1 = EMAX(tA1, zero4); pA2 = EMAX(tA2, zero4);\
        pB0 = EMAX(tB0, zero4); pB1 = EMAX(tB1, zero4); pB2 = EMAX(tB2, zero4);\
        SB                                                                    \
        GATE1_2(0)   /* i */                                                  \
        SIG3(qA0, qA1, qA2, tA0, tA1, tA2)                                    \
        SIG3(qB0, qB1, qB2, tB0, tB1, tB2)                                    \
        pA0 *= qA0; pA1 *= qA1; pA2 *= qA2;                                   \
        pB0 *= qB0; pB1 *= qB1; pB2 *= qB2; SB                                \
        GATE1_2(1)   /* f */                                                  \
        SIG3(qA0, qA1, qA2, tA0, tA1, tA2)                                    \
        SIG3(qB0, qB1, qB2, tB0, tB1, tB2)                                    \
        cA0 = EFMA(qA0, cA0, pA0); cA1 = EFMA(qA1, cA1, pA1);                 \
        cA2 = EFMA(qA2, cA2, pA2);                                            \
        cB0 = EFMA(qB0, cB0, pB0); cB1 = EFMA(qB1, cB1, pB1);                 \
        cB2 = EFMA(qB2, cB2, pB2); SB                                         \
        GATE1_2(3)   /* o (dot uses old h; h written after) */                \
        SIG3(qA0, qA1, qA2, tA0, tA1, tA2)                                    \
        SIG3(qB0, qB1, qB2, tB0, tB1, tB2)                                    \
        hA0 = qA0 * EMAX(cA0, zero4); hA1 = qA1 * EMAX(cA1, zero4);           \
        hA2 = qA2 * EMAX(cA2, zero4);                                         \
        hB0 = qB0 * EMAX(cB0, zero4); hB1 = qB1 * EMAX(cB1, zero4);           \
        hB2 = qB2 * EMAX(cB2, zero4); SB                                      \
    }

__global__ __launch_bounds__(BLK) __attribute__((amdgpu_waves_per_eu(2, 2)))
void lstm_ae_kernel(const float* __restrict__ X, const float* __restrict__ ws,
                    const float* __restrict__ bd, float* __restrict__ out, int B)
{
    __shared__ __align__(16) float smem[WS_FLOATS];    // 6.4 KB
    for (int i = threadIdx.x; i < WS_FLOATS; i += BLK) smem[i] = ws[i];
    __syncthreads();

    // M=2: rows b0 (element A) and b1 = b0 + BLK (element B)
    const int base = blockIdx.x * (2 * BLK);
    const int b0 = base + threadIdx.x;
    if (b0 >= B) return;
    int b1 = b0 + BLK;
    if (b1 >= B) b1 = b0;     // benign duplicate in non-exact tails

    const floatx4 zero4 = {0.0f, 0.0f, 0.0f, 0.0f};

    // ---------------- LSTM 1: 50 steps, 2 elements/thread ----------------
    floatx4 hA0 = zero4, hA1 = zero4, hA2 = zero4;
    floatx4 cA0 = zero4, cA1 = zero4, cA2 = zero4;
    floatx4 hB0 = zero4, hB1 = zero4, hB2 = zero4;
    floatx4 cB0 = zero4, cB1 = zero4, cB2 = zero4;

    const float2* __restrict__ xpa = (const float2*)(X + (size_t)b0 * TIN);
    const float2* __restrict__ xpb = (const float2*)(X + (size_t)b1 * TIN);
    float2 va = xpa[0], vb = xpb[0];
    #pragma unroll 1
    for (int p = 0; p < TIN / 2 - 1; ++p) {
        const float2 na = xpa[p + 1], nb = xpb[p + 1];
        STEP1_2(va.x, vb.x)
        STEP1_2(va.y, vb.y)
        va = na; vb = nb;
    }
    STEP1_2(va.x, vb.x)
    STEP1_2(va.y, vb.y)

    // ---------------- tails, sequential per element ----------------
    const float bd0 = bd[0];
    tail_one(smem, hA0, hA1, hA2, bd0, out + (size_t)b0 * 3);
    tail_one(smem, hB0, hB1, hB2, bd0, out + (size_t)b1 * 3);
}

extern "C" void kernel_launch(void* const* d_in, const int* in_sizes, int n_in,
                              void* d_out, int out_size, void* d_ws, size_t ws_size,
                              hipStream_t stream) {
    const float* X  = (const float*)d_in[0];
    const float* W1 = (const float*)d_in[1];
    const float* R1 = (const float*)d_in[2];
    const float* b1 = (const float*)d_in[3];
    const float* W2 = (const float*)d_in[4];
    const float* R2 = (const float*)d_in[5];
    const float* b2 = (const float*)d_in[6];
    const float* Wd = (const float*)d_in[7];
    const float* bd = (const float*)d_in[8];
    float* out = (float*)d_out;
    float* ws  = (float*)d_ws;

    const int B = in_sizes[0] / TIN;   // 524288
    prep_weights<<<1, BLK, 0, stream>>>(W1, R1, b1, W2, R2, b2, Wd, ws);
    const int grid = (B + 2 * BLK - 1) / (2 * BLK);   // 1024
    lstm_ae_kernel<<<grid, BLK, 0, stream>>>(X, ws, bd, out, B);
}

// Round 14
// 462.024 us; speedup vs baseline: 16.9773x; 1.0247x over previous
//
#include <hip/hip_runtime.h>

constexpr int TIN = 50;
constexpr int BLK = 256;
constexpr float NEG_LOG2E = -1.44269504088896341f;

typedef float floatx4 __attribute__((ext_vector_type(4)));

// ws float layout (16B-aligned, gate-major, 10->12 pad so quads are single-gate).
// k = gate*12 + j, gate {0:i,1:f,2:g,3:o}; i/f/o cols pre-scaled by -log2(e)
// so sigmoid(z) = rcp(1 + exp2(z')).
//   0    R1p[10][48]
//   480  W1p[48]
//   528  b1p[48]
//   576  W2p[10][48]
//   1056 b2p[48]
//   1104 R2p[10][48]
//   1584 Wdp[12]
constexpr int WS_FLOATS = 1596;

__global__ void prep_weights(const float* __restrict__ W1, const float* __restrict__ R1,
                             const float* __restrict__ b1, const float* __restrict__ W2,
                             const float* __restrict__ R2, const float* __restrict__ b2,
                             const float* __restrict__ Wd, float* __restrict__ ws)
{
    const int tid = threadIdx.x;
    for (int i = tid; i < 480; i += BLK) {
        const int u = i / 48, k = i % 48, gate = k / 12, j = k % 12;
        const float sg = (gate == 2) ? 1.0f : NEG_LOG2E;
        ws[i]        = (j < 10) ? R1[u * 40 + gate * 10 + j] * sg : 0.0f;
        ws[576 + i]  = (j < 10) ? W2[u * 40 + gate * 10 + j] * sg : 0.0f;
        ws[1104 + i] = (j < 10) ? R2[u * 40 + gate * 10 + j] * sg : 0.0f;
    }
    for (int k = tid; k < 48; k += BLK) {
        const int gate = k / 12, j = k % 12;
        const float sg = (gate == 2) ? 1.0f : NEG_LOG2E;
        ws[480 + k]  = (j < 10) ? W1[gate * 10 + j] * sg : 0.0f;
        ws[528 + k]  = (j < 10) ? b1[gate * 10 + j] * sg : 0.0f;
        ws[1056 + k] = (j < 10) ? b2[gate * 10 + j] * sg : 0.0f;
    }
    if (tid < 12) ws[1584 + tid] = (tid < 10) ? Wd[tid] : 0.0f;
}

#define EFMA __builtin_elementwise_fma
#define EMAX __builtin_elementwise_max
#define SB   __builtin_amdgcn_sched_barrier(0);

#define SIGQ(dst, src)                                                        \
    dst[0] = __builtin_amdgcn_rcpf(1.0f + __builtin_amdgcn_exp2f((src)[0]));  \
    dst[1] = __builtin_amdgcn_rcpf(1.0f + __builtin_amdgcn_exp2f((src)[1]));  \
    dst[2] = __builtin_amdgcn_rcpf(1.0f + __builtin_amdgcn_exp2f((src)[2]));  \
    dst[3] = __builtin_amdgcn_rcpf(1.0f + __builtin_amdgcn_exp2f((src)[3]));

#define SIG3(d0, d1, d2, s0, s1, s2) SIGQ(d0, s0) SIGQ(d1, s1) SIGQ(d2, s2)

// ---------------- single-element building blocks (epilogue; = round 10) -----
#define RECQ(RB, g, u, HV, t0, t1, t2)                                        \
    {   const float h_ = (HV);                                                \
        const floatx4 hs_ = {h_, h_, h_, h_};                                 \
        t0 = EFMA(hs_, RB[(u) * 12 + (g) * 3 + 0], t0);                       \
        t1 = EFMA(hs_, RB[(u) * 12 + (g) * 3 + 1], t1);                       \
        t2 = EFMA(hs_, RB[(u) * 12 + (g) * 3 + 2], t2); }

#define REC10(RB, g, H0, H1, H2, t0, t1, t2)                                  \
    RECQ(RB, g, 0, (H0)[0], t0, t1, t2) RECQ(RB, g, 1, (H0)[1], t0, t1, t2) SB\
    RECQ(RB, g, 2, (H0)[2], t0, t1, t2) RECQ(RB, g, 3, (H0)[3], t0, t1, t2) SB\
    RECQ(RB, g, 4, (H1)[0], t0, t1, t2) RECQ(RB, g, 5, (H1)[1], t0, t1, t2) SB\
    RECQ(RB, g, 6, (H1)[2], t0, t1, t2) RECQ(RB, g, 7, (H1)[3], t0, t1, t2) SB\
    RECQ(RB, g, 8, (H2)[0], t0, t1, t2) RECQ(RB, g, 9, (H2)[1], t0, t1, t2) SB

#define XZG(g, x0, x1, x2)                                                    \
    x0 = B2q_[(g) * 3 + 0]; x1 = B2q_[(g) * 3 + 1]; x2 = B2q_[(g) * 3 + 2];   \
    REC10(W2q_, g, hq0, hq1, hq2, x0, x1, x2)

#define GATE2(g, i0, i1, i2, t0, t1, t2)                                      \
    t0 = i0; t1 = i1; t2 = i2;                                                \
    REC10(R2q_, g, ho0, ho1, ho2, t0, t1, t2)

#define STEP2T                                                                \
    {   const floatx4 ho0 = h2q0, ho1 = h2q1, ho2 = h2q2;                     \
        floatx4 tt0, tt1, tt2, pp0, pp1, pp2, qq0, qq1, qq2;                  \
        GATE2(2, xqg0, xqg1, xqg2, tt0, tt1, tt2)                             \
        pp0 = EMAX(tt0, zero4); pp1 = EMAX(tt1, zero4);                       \
        pp2 = EMAX(tt2, zero4); SB                                            \
        GATE2(0, xqi0, xqi1, xqi2, tt0, tt1, tt2)                             \
        SIG3(qq0, qq1, qq2, tt0, tt1, tt2)                                    \
        pp0 *= qq0; pp1 *= qq1; pp2 *= qq2; SB                                \
        GATE2(1, xqf0, xqf1, xqf2, tt0, tt1, tt2)                             \
        SIG3(qq0, qq1, qq2, tt0, tt1, tt2)                                    \
        c2q0 = EFMA(qq0, c2q0, pp0); c2q1 = EFMA(qq1, c2q1, pp1);             \
        c2q2 = EFMA(qq2, c2q2, pp2); SB                                       \
        GATE2(3, xqo0, xqo1, xqo2, tt0, tt1, tt2)                             \
        SIG3(qq0, qq1, qq2, tt0, tt1, tt2)                                    \
        h2q0 = qq0 * EMAX(c2q0, zero4); h2q1 = qq1 * EMAX(c2q1, zero4);       \
        h2q2 = qq2 * EMAX(c2q2, zero4); SB                                    \
    }

#define DOUT(dst)                                                             \
    {   floatx4 dv_ = h2q0 * Wdq_[0];                                         \
        dv_ = EFMA(h2q1, Wdq_[1], dv_);                                       \
        dv_ = EFMA(h2q2, Wdq_[2], dv_);                                       \
        dst = dv_[0] + dv_[1] + dv_[2] + dv_[3] + bd0; }

// RepeatVector(3) + LSTM2 + Dense for ONE element (all names compile-time)
__device__ __forceinline__ void tail_one(const float* __restrict__ smem,
                                         floatx4 hq0, floatx4 hq1, floatx4 hq2,
                                         float bd0, float* __restrict__ o3)
{
    const floatx4 zero4 = {0.0f, 0.0f, 0.0f, 0.0f};
    const floatx4* W2q_ = (const floatx4*)(smem + 576);
    const floatx4* B2q_ = (const floatx4*)(smem + 1056);
    const floatx4* R2q_ = (const floatx4*)(smem + 1104);
    const floatx4* Wdq_ = (const floatx4*)(smem + 1584);

    floatx4 xqi0, xqi1, xqi2, xqf0, xqf1, xqf2;
    floatx4 xqg0, xqg1, xqg2, xqo0, xqo1, xqo2;
    XZG(0, xqi0, xqi1, xqi2) SB
    XZG(1, xqf0, xqf1, xqf2) SB
    XZG(2, xqg0, xqg1, xqg2) SB
    XZG(3, xqo0, xqo1, xqo2) SB

    floatx4 c2q0, c2q1, c2q2, h2q0, h2q1, h2q2, q0, q1, q2, s0, s1, s2;
    SIG3(q0, q1, q2, xqi0, xqi1, xqi2)
    c2q0 = q0 * EMAX(xqg0, zero4);
    c2q1 = q1 * EMAX(xqg1, zero4);
    c2q2 = q2 * EMAX(xqg2, zero4);
    SIG3(s0, s1, s2, xqo0, xqo1, xqo2)
    h2q0 = s0 * EMAX(c2q0, zero4);
    h2q1 = s1 * EMAX(c2q1, zero4);
    h2q2 = s2 * EMAX(c2q2, zero4);
    float o0; DOUT(o0)
    float o1; STEP2T DOUT(o1)
    float o2; STEP2T DOUT(o2)
    o3[0] = o0; o3[1] = o1; o3[2] = o2;
}

// ---------------- M=2 main-loop building blocks ----------------------------
// One source unit, shared quad loads (CSE -> 3 ds_read_b128), 6 quad-FMAs.
#define RECQ2(RB, g, u, HA, HB)                                               \
    {   const float ha_ = (HA), hb_ = (HB);                                   \
        const floatx4 hav_ = {ha_, ha_, ha_, ha_};                            \
        const floatx4 hbv_ = {hb_, hb_, hb_, hb_};                            \
        const floatx4 r0_ = RB[(u) * 12 + (g) * 3 + 0];                       \
        const floatx4 r1_ = RB[(u) * 12 + (g) * 3 + 1];                       \
        const floatx4 r2_ = RB[(u) * 12 + (g) * 3 + 2];                       \
        tA0 = EFMA(hav_, r0_, tA0); tB0 = EFMA(hbv_, r0_, tB0);               \
        tA1 = EFMA(hav_, r1_, tA1); tB1 = EFMA(hbv_, r1_, tB1);               \
        tA2 = EFMA(hav_, r2_, tA2); tB2 = EFMA(hbv_, r2_, tB2); }

#define REC10_2(RB, g)                                                        \
    RECQ2(RB, g, 0, hA0[0], hB0[0]) RECQ2(RB, g, 1, hA0[1], hB0[1]) SB        \
    RECQ2(RB, g, 2, hA0[2], hB0[2]) RECQ2(RB, g, 3, hA0[3], hB0[3]) SB        \
    RECQ2(RB, g, 4, hA1[0], hB1[0]) RECQ2(RB, g, 5, hA1[1], hB1[1]) SB        \
    RECQ2(RB, g, 6, hA1[2], hB1[2]) RECQ2(RB, g, 7, hA1[3], hB1[3]) SB        \
    RECQ2(RB, g, 8, hA2[0], hB2[0]) RECQ2(RB, g, 9, hA2[1], hB2[1]) SB

#define GATE1_2(g)                                                            \
    tA0 = EFMA(xsA_, Wq_[(g) * 3 + 0], Bq_[(g) * 3 + 0]);                     \
    tB0 = EFMA(xsB_, Wq_[(g) * 3 + 0], Bq_[(g) * 3 + 0]);                     \
    tA1 = EFMA(xsA_, Wq_[(g) * 3 + 1], Bq_[(g) * 3 + 1]);                     \
    tB1 = EFMA(xsB_, Wq_[(g) * 3 + 1], Bq_[(g) * 3 + 1]);                     \
    tA2 = EFMA(xsA_, Wq_[(g) * 3 + 2], Bq_[(g) * 3 + 2]);                     \
    tB2 = EFMA(xsB_, Wq_[(g) * 3 + 2], Bq_[(g) * 3 + 2]);                     \
    REC10_2(Rq_, g)

#define STEP1_2(xa, xb)                                                       \
    {   int lof_ = 0;                                                         \
        asm volatile("" : "+v"(lof_));    /* block LICM of invariant loads */ \
        const floatx4* Rq_ = (const floatx4*)(smem + lof_);                   \
        const floatx4* Wq_ = (const floatx4*)(smem + 480 + lof_);             \
        const floatx4* Bq_ = (const floatx4*)(smem + 528 + lof_);             \
        const float xa_ = (xa), xb_ = (xb);                                   \
        const floatx4 xsA_ = {xa_, xa_, xa_, xa_};                            \
        const floatx4 xsB_ = {xb_, xb_, xb_, xb_};                            \
        floatx4 tA0, tA1, tA2, tB0, tB1, tB2;                                 \
        floatx4 pA0, pA1, pA2, pB0, pB1, pB2;                                 \
        floatx4 qA0, qA1, qA2, qB0, qB1, qB2;                                 \
        GATE1_2(2)   /* g: relu */                                            \
        pA0 = EMAX(tA0, zero4); pA1 = EMAX(tA1, zero4); pA2 = EMAX(tA2, zero4);\
        pB0 = EMAX(tB0, zero4); pB1 = EMAX(tB1, zero4); pB2 = EMAX(tB2, zero4);\
        SB                                                                    \
        GATE1_2(0)   /* i */                                                  \
        SIG3(qA0, qA1, qA2, tA0, tA1, tA2)                                    \
        SIG3(qB0, qB1, qB2, tB0, tB1, tB2)                                    \
        pA0 *= qA0; pA1 *= qA1; pA2 *= qA2;                                   \
        pB0 *= qB0; pB1 *= qB1; pB2 *= qB2; SB                                \
        GATE1_2(1)   /* f */                                                  \
        SIG3(qA0, qA1, qA2, tA0, tA1, tA2)                                    \
        SIG3(qB0, qB1, qB2, tB0, tB1, tB2)                                    \
        cA0 = EFMA(qA0, cA0, pA0); cA1 = EFMA(qA1, cA1, pA1);                 \
        cA2 = EFMA(qA2, cA2, pA2);                                            \
        cB0 = EFMA(qB0, cB0, pB0); cB1 = EFMA(qB1, cB1, pB1);                 \
        cB2 = EFMA(qB2, cB2, pB2); SB                                         \
        GATE1_2(3)   /* o (dot uses old h; h written after) */                \
        SIG3(qA0, qA1, qA2, tA0, tA1, tA2)                                    \
        SIG3(qB0, qB1, qB2, tB0, tB1, tB2)                                    \
        hA0 = qA0 * EMAX(cA0, zero4); hA1 = qA1 * EMAX(cA1, zero4);           \
        hA2 = qA2 * EMAX(cA2, zero4);                                         \
        hB0 = qB0 * EMAX(cB0, zero4); hB1 = qB1 * EMAX(cB1, zero4);           \
        hB2 = qB2 * EMAX(cB2, zero4); SB                                      \
    }

// round 14: min=2 keeps the RA budget that produced the clean 88-VGPR M=2
// schedule; NO max so hardware residency is set by actual VGPR use
// (512/88 -> up to 5 waves/SIMD; grid supplies 4).
__global__ __launch_bounds__(BLK) __attribute__((amdgpu_waves_per_eu(2)))
void lstm_ae_kernel(const float* __restrict__ X, const float* __restrict__ ws,
                    const float* __restrict__ bd, float* __restrict__ out, int B)
{
    __shared__ __align__(16) float smem[WS_FLOATS];    // 6.4 KB
    for (int i = threadIdx.x; i < WS_FLOATS; i += BLK) smem[i] = ws[i];
    __syncthreads();

    // M=2: rows b0 (element A) and b1 = b0 + BLK (element B)
    const int base = blockIdx.x * (2 * BLK);
    const int b0 = base + threadIdx.x;
    if (b0 >= B) return;
    int b1 = b0 + BLK;
    if (b1 >= B) b1 = b0;     // benign duplicate in non-exact tails

    const floatx4 zero4 = {0.0f, 0.0f, 0.0f, 0.0f};

    // ---------------- LSTM 1: 50 steps, 2 elements/thread ----------------
    floatx4 hA0 = zero4, hA1 = zero4, hA2 = zero4;
    floatx4 cA0 = zero4, cA1 = zero4, cA2 = zero4;
    floatx4 hB0 = zero4, hB1 = zero4, hB2 = zero4;
    floatx4 cB0 = zero4, cB1 = zero4, cB2 = zero4;

    const float2* __restrict__ xpa = (const float2*)(X + (size_t)b0 * TIN);
    const float2* __restrict__ xpb = (const float2*)(X + (size_t)b1 * TIN);
    float2 va = xpa[0], vb = xpb[0];
    #pragma unroll 1
    for (int p = 0; p < TIN / 2 - 1; ++p) {
        const float2 na = xpa[p + 1], nb = xpb[p + 1];
        STEP1_2(va.x, vb.x)
        STEP1_2(va.y, vb.y)
        va = na; vb = nb;
    }
    STEP1_2(va.x, vb.x)
    STEP1_2(va.y, vb.y)

    // ---------------- tails, sequential per element ----------------
    const float bd0 = bd[0];
    tail_one(smem, hA0, hA1, hA2, bd0, out + (size_t)b0 * 3);
    tail_one(smem, hB0, hB1, hB2, bd0, out + (size_t)b1 * 3);
}

extern "C" void kernel_launch(void* const* d_in, const int* in_sizes, int n_in,
                              void* d_out, int out_size, void* d_ws, size_t ws_size,
                              hipStream_t stream) {
    const float* X  = (const float*)d_in[0];
    const float* W1 = (const float*)d_in[1];
    const float* R1 = (const float*)d_in[2];
    const float* b1 = (const float*)d_in[3];
    const float* W2 = (const float*)d_in[4];
    const float* R2 = (const float*)d_in[5];
    const float* b2 = (const float*)d_in[6];
    const float* Wd = (const float*)d_in[7];
    const float* bd = (const float*)d_in[8];
    float* out = (float*)d_out;
    float* ws  = (float*)d_ws;

    const int B = in_sizes[0] / TIN;   // 524288
    prep_weights<<<1, BLK, 0, stream>>>(W1, R1, b1, W2, R2, b2, Wd, ws);
    const int grid = (B + 2 * BLK - 1) / (2 * BLK);   // 1024
    lstm_ae_kernel<<<grid, BLK, 0, stream>>>(X, ws, bd, out, B);
}